// Round 2
// baseline (598.887 us; speedup 1.0000x reference)
//
#include <hip/hip_runtime.h>
#include <hip/hip_bf16.h>
#include <math.h>

// Problem dims
#define BB 2
#define NN 128
#define HH 768
#define KK 64
#define H2 256
#define H3 128
#define H4 32
#define NC 7
#define FC1N 1000
#define FC2N 100

#define SPLIT 256
#define HBLK 192   // 49152 / SPLIT

__device__ __forceinline__ float gelu_exact(float x) {
    return 0.5f * x * (1.0f + erff(x * 0.70710678118654752f));
}

// ---------------------------------------------------------------------------
// K1: distance matrix + min-max normalize (over clusters) + gaussian sim,
//     written transposed: pT[b][k][n] = sim(b,n,k). One block per (b,n).
// ---------------------------------------------------------------------------
__global__ void __launch_bounds__(256) k_dist(const float* __restrict__ enc,
                                              const float* __restrict__ mask,
                                              const float* __restrict__ lm,
                                              const float* __restrict__ dptr,
                                              float* __restrict__ pT) {
    __shared__ __align__(16) float es[HH];
    __shared__ float pd[4][KK];
    int blk = blockIdx.x;
    int b = blk >> 7, n = blk & 127;
    int t = threadIdx.x;
    const float4* erow4 = reinterpret_cast<const float4*>(enc + ((size_t)b * NN + n) * HH);
    if (t < HH / 4) reinterpret_cast<float4*>(es)[t] = erow4[t];
    __syncthreads();
    int k = t & 63, part = t >> 6;
    const float4* l4 = reinterpret_cast<const float4*>(lm + (size_t)k * HH + part * 192);
    const float4* e4 = reinterpret_cast<const float4*>(es + part * 192);
    float s = 0.f;
    #pragma unroll 8
    for (int h = 0; h < 48; ++h) {
        float4 a = e4[h], w = l4[h];
        float d0 = a.x - w.x, d1 = a.y - w.y, d2 = a.z - w.z, d3 = a.w - w.w;
        s += d0 * d0 + d1 * d1 + d2 * d2 + d3 * d3;
    }
    pd[part][k] = s;
    __syncthreads();
    if (t < 64) {
        float d2 = pd[0][t] + pd[1][t] + pd[2][t] + pd[3][t];
        float dist = sqrtf(d2);
        float mn = dist, mx = dist;
        for (int o = 32; o; o >>= 1) {
            mn = fminf(mn, __shfl_xor(mn, o));
            mx = fmaxf(mx, __shfl_xor(mx, o));
        }
        float dn = (dist - mn) / (mx - mn + 1e-6f);
        float dval = dptr[0];
        float sim = expf(-(dn * dn) / (2.0f * dval * dval)) * mask[b * NN + n];
        pT[((size_t)b * KK + t) * NN + n] = sim;
    }
}

// ---------------------------------------------------------------------------
// K2: normalize P over token dim: pT[row][n] /= (sum_n + eps).
// ---------------------------------------------------------------------------
__global__ void k_pnorm(float* __restrict__ pT) {
    int row = blockIdx.x;
    int t = threadIdx.x;
    float* r = pT + (size_t)row * NN;
    float v0 = r[t], v1 = r[t + 64];
    float s = v0 + v1;
    for (int o = 32; o; o >>= 1) s += __shfl_xor(s, o);
    float den = s + 1e-6f;
    r[t] = v0 / den;
    r[t + 64] = v1 / den;
}

// ---------------------------------------------------------------------------
// K3: graph construction. G[b,i,j] = sum_{s,t} exp(beta*p_i[s]*p_j[t]*Wd[s,t]) - 1.
//     G is symmetric in (i,j): blocks with i>j exit, i<=j writes both cells.
//     wvx[128+delta] = exp(-alpha*|delta|) removes the abs() from the hot loop.
//     Only (G != 0) is consumed downstream; terms share beta's sign, so the
//     value precision of __expf is irrelevant to the nonzero pattern.
// ---------------------------------------------------------------------------
__global__ void __launch_bounds__(256) k_graph(const float* __restrict__ pT,
                                               const float* __restrict__ aptr,
                                               const float* __restrict__ bptr,
                                               float* __restrict__ G) {
    int blk = blockIdx.x;
    int b = blk >> 12;
    int i = (blk >> 6) & 63, j = blk & 63;
    if (i > j) return;                       // uniform early exit (symmetry)
    __shared__ float wvx[256], pi[NN], pj[NN];
    __shared__ float red[4];
    int t = threadIdx.x;
    float alpha = aptr[0], beta = bptr[0];
    wvx[t] = __expf(-alpha * fabsf((float)(t - 128)));
    if (t < 128) pi[t] = pT[((size_t)b * KK + i) * NN + t];
    else         pj[t - 128] = pT[((size_t)b * KK + j) * NN + (t - 128)];
    __syncthreads();
    int tt = t & 127;
    int s0 = t >> 7;
    float pjv = pj[tt] * beta;
    const float* wp = wvx + (128 + s0 - tt);
    float acc = 0.f;
    #pragma unroll
    for (int it = 0; it < 64; ++it) {
        int s = s0 + 2 * it;
        acc += __expf(pjv * pi[s] * wp[2 * it]);
    }
    acc -= 64.0f;                            // the "-1" per term, hoisted
    for (int o = 32; o; o >>= 1) acc += __shfl_xor(acc, o);
    if ((t & 63) == 0) red[t >> 6] = acc;
    __syncthreads();
    if (t == 0) {
        float total = red[0] + red[1] + red[2] + red[3];
        G[((size_t)b * KK + i) * KK + j] = total;
        G[((size_t)b * KK + j) * KK + i] = total;
    }
}

// ---------------------------------------------------------------------------
// K4: binary adjacency (diag forced 1) + symmetric normalization.
// ---------------------------------------------------------------------------
__global__ void k_nadj(const float* __restrict__ G, float* __restrict__ nadj) {
    __shared__ float dinv[KK];
    int b = blockIdx.x;
    int i = threadIdx.x;
    const float* gr = G + ((size_t)b * KK + i) * KK;
    float deg = 0.f;
    for (int j = 0; j < KK; ++j) {
        float a = (j == i) ? 1.f : ((gr[j] != 0.f) ? 1.f : 0.f);
        deg += a;
    }
    dinv[i] = (deg > 0.f) ? (1.0f / sqrtf(deg)) : 0.f;
    __syncthreads();
    float di = dinv[i];
    float* nr = nadj + ((size_t)b * KK + i) * KK;
    for (int j = 0; j < KK; ++j) {
        float a = (j == i) ? 1.f : ((gr[j] != 0.f) ? 1.f : 0.f);
        nr[j] = di * a * dinv[j];
    }
}

// ---------------------------------------------------------------------------
// K5: node features nf[b,k,h] = sum_n pT[b,k,n] * enc[b,n,h]. Block per (b,k).
// ---------------------------------------------------------------------------
__global__ void __launch_bounds__(256) k_nodefeat(const float* __restrict__ pT,
                                                  const float* __restrict__ enc,
                                                  float* __restrict__ nf) {
    __shared__ float pr[NN];
    int blk = blockIdx.x;           // b*64 + k
    int b = blk >> 6;
    int t = threadIdx.x;
    if (t < NN) pr[t] = pT[(size_t)blk * NN + t];
    __syncthreads();
    const float* eb = enc + (size_t)b * NN * HH;
    float a0 = 0.f, a1 = 0.f, a2 = 0.f;
    for (int n = 0; n < NN; ++n) {
        float p = pr[n];
        const float* er = eb + (size_t)n * HH;
        a0 += p * er[t];
        a1 += p * er[t + 256];
        a2 += p * er[t + 512];
    }
    float* o = nf + (size_t)blk * HH;
    o[t] = a0; o[t + 256] = a1; o[t + 512] = a2;
}

// ---------------------------------------------------------------------------
// K6: dense mm, 4 rows/block, float4 over cols: O[m,j] = sum_h X[m,h]*W[h,j].
//     blockDim must be Jd.
// ---------------------------------------------------------------------------
template<int Hd, int Jd>
__global__ void k_mm4v(const float* __restrict__ X, const float* __restrict__ W,
                       float* __restrict__ O) {
    __shared__ __align__(16) float s[4 * Hd];
    int m0 = blockIdx.x * 4;
    for (int idx = threadIdx.x; idx < Hd; idx += blockDim.x)
        reinterpret_cast<float4*>(s)[idx] =
            reinterpret_cast<const float4*>(X + (size_t)m0 * Hd)[idx];
    __syncthreads();
    int r  = threadIdx.x / (Jd / 4);
    int jg = threadIdx.x % (Jd / 4);
    const float* xr = s + r * Hd;
    const float4* W4 = reinterpret_cast<const float4*>(W) + jg;
    float4 acc = {0.f, 0.f, 0.f, 0.f};
    #pragma unroll 4
    for (int h = 0; h < Hd; ++h) {
        float4 w = W4[(size_t)h * (Jd / 4)];
        float x = xr[h];
        acc.x += x * w.x; acc.y += x * w.y; acc.z += x * w.z; acc.w += x * w.w;
    }
    reinterpret_cast<float4*>(O + (size_t)(m0 + r) * Jd)[jg] = acc;
}

// ---------------------------------------------------------------------------
// K7: O[b,i,:] = relu( nadj[b,i,:] @ X[b] + bias ). Block per (b,i), Jd/4 thr.
// ---------------------------------------------------------------------------
template<int Jd>
__global__ void k_adjrelu(const float* __restrict__ nadj, const float* __restrict__ X,
                          const float* __restrict__ bias, float* __restrict__ O) {
    __shared__ float ar[KK];
    int blk = blockIdx.x;           // b*64 + i
    int b = blk >> 6;
    for (int idx = threadIdx.x; idx < KK; idx += blockDim.x)
        ar[idx] = nadj[(size_t)blk * KK + idx];
    __syncthreads();
    int t = threadIdx.x;            // [0, Jd/4)
    const float4* xb4 = reinterpret_cast<const float4*>(X + (size_t)b * KK * Jd) + t;
    float4 acc = reinterpret_cast<const float4*>(bias)[t];
    #pragma unroll 8
    for (int jj = 0; jj < KK; ++jj) {
        float a = ar[jj];
        float4 x = xb4[(size_t)jj * (Jd / 4)];
        acc.x += a * x.x; acc.y += a * x.y; acc.z += a * x.z; acc.w += a * x.w;
    }
    acc.x = fmaxf(acc.x, 0.f); acc.y = fmaxf(acc.y, 0.f);
    acc.z = fmaxf(acc.z, 0.f); acc.w = fmaxf(acc.w, 0.f);
    reinterpret_cast<float4*>(O + (size_t)blk * Jd)[t] = acc;
}

// ---------------------------------------------------------------------------
// K8: fc1 split-K with fused residual head. Block s computes its own
//     192-col slice of out = h3 @ adj_w + adj_b + nf (each slice is needed by
//     exactly one block), then streams W rows [s*192,(s+1)*192) x 1000 cols.
// ---------------------------------------------------------------------------
__global__ void __launch_bounds__(256) k_fc1(const float* __restrict__ h3,
                                             const float* __restrict__ adj_w,
                                             const float* __restrict__ adj_b,
                                             const float* __restrict__ nf,
                                             const float* __restrict__ W,
                                             float* __restrict__ part) {
    __shared__ __align__(16) float xs[2 * HBLK];
    __shared__ float h3s[2][H4];
    int s = blockIdx.x;
    int krow = s >> 2;              // which (k) row of out this block touches
    int c0 = (s & 3) * HBLK;        // column offset within the 768-wide row
    int t = threadIdx.x;
    if (t < 2 * H4) h3s[t >> 5][t & 31] = h3[(size_t)((t >> 5) * KK + krow) * H4 + (t & 31)];
    __syncthreads();
    for (int idx = t; idx < 2 * HBLK; idx += 256) {
        int bb = idx / HBLK, h = idx - bb * HBLK;
        int hcol = c0 + h;
        float acc = adj_b[hcol] + nf[(size_t)(bb * KK + krow) * HH + hcol];
        #pragma unroll
        for (int kk = 0; kk < H4; ++kk) acc += h3s[bb][kk] * adj_w[(size_t)kk * HH + hcol];
        xs[idx] = acc;
    }
    __syncthreads();
    if (t < 250) {
        float4 a0 = {0.f, 0.f, 0.f, 0.f}, a1 = {0.f, 0.f, 0.f, 0.f};
        const float4* W4 = reinterpret_cast<const float4*>(W) + t;
        int h0 = s * HBLK;
        for (int hh = 0; hh < HBLK; ++hh) {
            float4 w = W4[(size_t)(h0 + hh) * 250];
            float x0 = xs[hh], x1 = xs[HBLK + hh];
            a0.x += x0 * w.x; a0.y += x0 * w.y; a0.z += x0 * w.z; a0.w += x0 * w.w;
            a1.x += x1 * w.x; a1.y += x1 * w.y; a1.z += x1 * w.z; a1.w += x1 * w.w;
        }
        float* p0 = part + (size_t)s * (2 * FC1N);
        reinterpret_cast<float4*>(p0)[t] = a0;
        reinterpret_cast<float4*>(p0 + FC1N)[t] = a1;
    }
}

// K9: reduce fc1 partials + bias + exact gelu -> y1[2,1000]
__global__ void k_fc1red(const float* __restrict__ part, const float* __restrict__ bias,
                         float* __restrict__ y1) {
    int g = blockIdx.x * 256 + threadIdx.x;
    if (g >= 2 * FC1N) return;
    int b = g / FC1N, j = g % FC1N;
    float acc = bias[j];
    for (int s = 0; s < SPLIT; ++s) acc += part[(size_t)s * (2 * FC1N) + b * FC1N + j];
    y1[g] = gelu_exact(acc);
}

// K10: fused fc2(gelu)+fc3 -> d_out[2,7]. One 512-thread block; fc2's
//      1000-deep dot is split over 4 lane groups of 250.
__global__ void __launch_bounds__(512) k_fc23(const float* __restrict__ y1,
                                              const float* __restrict__ W2,
                                              const float* __restrict__ b2,
                                              const float* __restrict__ W3,
                                              const float* __restrict__ b3,
                                              float* __restrict__ out) {
    __shared__ float ys[2 * FC1N];
    __shared__ float psum[4][2][128];
    __shared__ float y2s[2][FC2N];
    int t = threadIdx.x;
    for (int idx = t; idx < 2 * FC1N; idx += 512) ys[idx] = y1[idx];
    __syncthreads();
    int j = t & 127, kp = t >> 7;
    float a0 = 0.f, a1 = 0.f;
    if (j < FC2N) {
        const float* ya = ys + kp * 250;
        const float* yb = ys + FC1N + kp * 250;
        const float* wp = W2 + (size_t)(kp * 250) * FC2N + j;
        #pragma unroll 4
        for (int h = 0; h < 250; ++h) {
            float w = wp[(size_t)h * FC2N];
            a0 += ya[h] * w;
            a1 += yb[h] * w;
        }
    }
    psum[kp][0][j] = a0;
    psum[kp][1][j] = a1;
    __syncthreads();
    if (t < 2 * FC2N) {
        int bb = t / FC2N, jj = t % FC2N;
        float acc = b2[jj] + psum[0][bb][jj] + psum[1][bb][jj]
                  + psum[2][bb][jj] + psum[3][bb][jj];
        y2s[bb][jj] = gelu_exact(acc);
    }
    __syncthreads();
    if (t < BB * NC) {
        int bb = t / NC, c = t % NC;
        float acc = b3[c];
        for (int h = 0; h < FC2N; ++h) acc += y2s[bb][h] * W3[h * NC + c];
        out[t] = acc;
    }
}

extern "C" void kernel_launch(void* const* d_in, const int* in_sizes, int n_in,
                              void* d_out, int out_size, void* d_ws, size_t ws_size,
                              hipStream_t stream) {
    const float* enc   = (const float*)d_in[0];
    const float* mask  = (const float*)d_in[1];
    const float* lm    = (const float*)d_in[2];
    const float* dptr  = (const float*)d_in[3];
    const float* aptr  = (const float*)d_in[4];
    const float* bptr  = (const float*)d_in[5];
    const float* w1    = (const float*)d_in[6];
    const float* b1    = (const float*)d_in[7];
    const float* w2    = (const float*)d_in[8];
    const float* b2    = (const float*)d_in[9];
    const float* w3    = (const float*)d_in[10];
    const float* b3    = (const float*)d_in[11];
    const float* adj_w = (const float*)d_in[12];
    const float* adj_b = (const float*)d_in[13];
    const float* fc1w  = (const float*)d_in[14];
    const float* fc1b  = (const float*)d_in[15];
    const float* fc2w  = (const float*)d_in[16];
    const float* fc2b  = (const float*)d_in[17];
    const float* fc3w  = (const float*)d_in[18];
    const float* fc3b  = (const float*)d_in[19];
    float* out = (float*)d_out;

    float* w = (float*)d_ws;
    float* pT   = w;                  // 16384
    float* G    = pT + 16384;         // 8192
    float* nadj = G + 8192;           // 8192
    float* nf   = nadj + 8192;        // 98304
    float* xw1  = nf + 98304;         // 32768
    float* h1   = xw1 + 32768;        // 32768
    float* xw2  = h1 + 32768;         // 16384
    float* h2   = xw2 + 16384;        // 16384
    float* xw3  = h2 + 16384;         // 4096
    float* h3   = xw3 + 4096;         // 4096
    float* part = h3 + 4096;          // SPLIT*2*1000 = 512000
    float* y1   = part + 512000;      // 2000

    k_dist<<<BB * NN, 256, 0, stream>>>(enc, mask, lm, dptr, pT);
    k_pnorm<<<BB * KK, 64, 0, stream>>>(pT);
    k_graph<<<BB * KK * KK, 256, 0, stream>>>(pT, aptr, bptr, G);
    k_nadj<<<BB, 64, 0, stream>>>(G, nadj);
    k_nodefeat<<<BB * KK, 256, 0, stream>>>(pT, enc, nf);
    k_mm4v<HH, H2><<<32, H2, 0, stream>>>(nf, w1, xw1);
    k_adjrelu<H2><<<BB * KK, H2 / 4, 0, stream>>>(nadj, xw1, b1, h1);
    k_mm4v<H2, H3><<<32, H3, 0, stream>>>(h1, w2, xw2);
    k_adjrelu<H3><<<BB * KK, H3 / 4, 0, stream>>>(nadj, xw2, b2, h2);
    k_mm4v<H3, H4><<<32, H4, 0, stream>>>(h2, w3, xw3);
    k_adjrelu<H4><<<BB * KK, H4 / 4, 0, stream>>>(nadj, xw3, b3, h3);
    k_fc1<<<SPLIT, 256, 0, stream>>>(h3, adj_w, adj_b, nf, fc1w, part);
    k_fc1red<<<8, 256, 0, stream>>>(part, fc1b, y1);
    k_fc23<<<1, 512, 0, stream>>>(y1, fc2w, fc2b, fc3w, fc3b, out);
}

// Round 12
// 511.497 us; speedup vs baseline: 1.1709x; 1.1709x over previous
//
#include <hip/hip_runtime.h>
#include <hip/hip_bf16.h>
#include <math.h>

// Problem dims
#define BB 2
#define NN 128
#define HH 768
#define KK 64
#define H2 256
#define H3 128
#define H4 32
#define NC 7
#define FC1N 1000
#define FC2N 100

#define SPLIT 512
#define HBLK 96    // 49152 / SPLIT

__device__ __forceinline__ float gelu_exact(float x) {
    return 0.5f * x * (1.0f + erff(x * 0.70710678118654752f));
}

// ---------------------------------------------------------------------------
// K1: distance matrix + min-max normalize (over clusters) + gaussian sim,
//     written transposed UNNORMALIZED: pT[b][k][n] = sim(b,n,k).
//     (token-dim normalization is folded into the consumers)
// ---------------------------------------------------------------------------
__global__ void __launch_bounds__(256) k_dist(const float* __restrict__ enc,
                                              const float* __restrict__ mask,
                                              const float* __restrict__ lm,
                                              const float* __restrict__ dptr,
                                              float* __restrict__ pT) {
    __shared__ __align__(16) float es[HH];
    __shared__ float pd[4][KK];
    int blk = blockIdx.x;
    int b = blk >> 7, n = blk & 127;
    int t = threadIdx.x;
    const float4* erow4 = reinterpret_cast<const float4*>(enc + ((size_t)b * NN + n) * HH);
    if (t < HH / 4) reinterpret_cast<float4*>(es)[t] = erow4[t];
    __syncthreads();
    int k = t & 63, part = t >> 6;
    const float4* l4 = reinterpret_cast<const float4*>(lm + (size_t)k * HH + part * 192);
    const float4* e4 = reinterpret_cast<const float4*>(es + part * 192);
    float s = 0.f;
    #pragma unroll 8
    for (int h = 0; h < 48; ++h) {
        float4 a = e4[h], w = l4[h];
        float d0 = a.x - w.x, d1 = a.y - w.y, d2 = a.z - w.z, d3 = a.w - w.w;
        s += d0 * d0 + d1 * d1 + d2 * d2 + d3 * d3;
    }
    pd[part][k] = s;
    __syncthreads();
    if (t < 64) {
        float d2 = pd[0][t] + pd[1][t] + pd[2][t] + pd[3][t];
        float dist = sqrtf(d2);
        float mn = dist, mx = dist;
        for (int o = 32; o; o >>= 1) {
            mn = fminf(mn, __shfl_xor(mn, o));
            mx = fmaxf(mx, __shfl_xor(mx, o));
        }
        float dn = (dist - mn) / (mx - mn + 1e-6f);
        float dval = dptr[0];
        float sim = expf(-(dn * dn) / (2.0f * dval * dval)) * mask[b * NN + n];
        pT[((size_t)b * KK + t) * NN + n] = sim;
    }
}

// ---------------------------------------------------------------------------
// K2: graph construction with fused row-normalization.
//     G[b,i,j] = sum_{s,t} exp(beta*(pi[s]/di)*(pj[t]/dj)*Wd[s,t]) - 1
//     scale c = beta/(di*dj) folded into pj. Symmetric: i>j blocks exit.
//     Only (G != 0) is consumed downstream (all terms carry beta's sign since
//     p >= 0 and Wd > 0, so the nonzero pattern is order/precision-robust).
// ---------------------------------------------------------------------------
__global__ void __launch_bounds__(256) k_graph(const float* __restrict__ pT,
                                               const float* __restrict__ aptr,
                                               const float* __restrict__ bptr,
                                               float* __restrict__ G) {
    int blk = blockIdx.x;
    int b = blk >> 12;
    int i = (blk >> 6) & 63, j = blk & 63;
    if (i > j) return;                       // uniform early exit (symmetry)
    __shared__ float wvx[256], pi[NN], pj[NN];
    __shared__ float red[4], dens[2];
    int t = threadIdx.x;
    float alpha = aptr[0], beta = bptr[0];
    wvx[t] = __expf(-alpha * fabsf((float)(t - 128)));
    if (t < 128) pi[t] = pT[((size_t)b * KK + i) * NN + t];
    else         pj[t - 128] = pT[((size_t)b * KK + j) * NN + (t - 128)];
    __syncthreads();
    if (t < 64) {                            // wave 0: row-i sum
        float s = pi[t] + pi[t + 64];
        for (int o = 32; o; o >>= 1) s += __shfl_xor(s, o);
        if (t == 0) dens[0] = s + 1e-6f;
    } else if (t < 128) {                    // wave 1: row-j sum
        int u = t - 64;
        float s = pj[u] + pj[u + 64];
        for (int o = 32; o; o >>= 1) s += __shfl_xor(s, o);
        if (u == 0) dens[1] = s + 1e-6f;
    }
    __syncthreads();
    float c = beta / (dens[0] * dens[1]);
    int tt = t & 127;
    int s0 = t >> 7;
    float pjv = pj[tt] * c;
    const float* wp = wvx + (128 + s0 - tt);
    float acc = 0.f;
    #pragma unroll
    for (int it = 0; it < 64; ++it) {
        int s = s0 + 2 * it;
        acc += __expf(pjv * pi[s] * wp[2 * it]);
    }
    acc -= 64.0f;                            // the "-1" per term, hoisted
    for (int o = 32; o; o >>= 1) acc += __shfl_xor(acc, o);
    if ((t & 63) == 0) red[t >> 6] = acc;
    __syncthreads();
    if (t == 0) {
        float total = red[0] + red[1] + red[2] + red[3];
        G[((size_t)b * KK + i) * KK + j] = total;
        G[((size_t)b * KK + j) * KK + i] = total;
    }
}

// ---------------------------------------------------------------------------
// K3: node features with fused normalization:
//     nf[b,k,h] = (sum_n sim[b,k,n]*enc[b,n,h]) / (sum_n sim + eps)
// ---------------------------------------------------------------------------
__global__ void __launch_bounds__(256) k_nodefeat(const float* __restrict__ pT,
                                                  const float* __restrict__ enc,
                                                  float* __restrict__ nf) {
    __shared__ float pr[NN];
    __shared__ float dsh;
    int blk = blockIdx.x;           // b*64 + k
    int b = blk >> 6;
    int t = threadIdx.x;
    if (t < NN) pr[t] = pT[(size_t)blk * NN + t];
    __syncthreads();
    if (t < 64) {
        float s = pr[t] + pr[t + 64];
        for (int o = 32; o; o >>= 1) s += __shfl_xor(s, o);
        if (t == 0) dsh = s + 1e-6f;
    }
    __syncthreads();
    float inv = 1.0f / dsh;
    const float* eb = enc + (size_t)b * NN * HH;
    float a0 = 0.f, a1 = 0.f, a2 = 0.f;
    #pragma unroll 8
    for (int n = 0; n < NN; ++n) {
        float p = pr[n];
        const float* er = eb + (size_t)n * HH;
        a0 += p * er[t];
        a1 += p * er[t + 256];
        a2 += p * er[t + 512];
    }
    float* o = nf + (size_t)blk * HH;
    o[t] = a0 * inv; o[t + 256] = a1 * inv; o[t + 512] = a2 * inv;
}

// ---------------------------------------------------------------------------
// K4: binary adjacency (diag forced 1) + symmetric normalization.
// ---------------------------------------------------------------------------
__global__ void k_nadj(const float* __restrict__ G, float* __restrict__ nadj) {
    __shared__ float dinv[KK];
    int b = blockIdx.x;
    int i = threadIdx.x;
    const float* gr = G + ((size_t)b * KK + i) * KK;
    float deg = 0.f;
    for (int j = 0; j < KK; ++j) {
        float a = (j == i) ? 1.f : ((gr[j] != 0.f) ? 1.f : 0.f);
        deg += a;
    }
    dinv[i] = (deg > 0.f) ? (1.0f / sqrtf(deg)) : 0.f;
    __syncthreads();
    float di = dinv[i];
    float* nr = nadj + ((size_t)b * KK + i) * KK;
    for (int j = 0; j < KK; ++j) {
        float a = (j == i) ? 1.f : ((gr[j] != 0.f) ? 1.f : 0.f);
        nr[j] = di * a * dinv[j];
    }
}

// ---------------------------------------------------------------------------
// K5: k-split partial GEMM: part[p][m][j] = sum_{h in slice p} X[m,h]*W[h,j]
//     Grid = (M/4) x KP blocks, blockDim = Jd. Deep unroll for MLP.
// ---------------------------------------------------------------------------
template<int Hd, int Jd, int KP>
__global__ void k_mmks(const float* __restrict__ X, const float* __restrict__ W,
                       float* __restrict__ part) {
    const int SLICE = Hd / KP;
    __shared__ float xs[4][SLICE];
    int blk = blockIdx.x;
    int mq = blk & 31, p = blk >> 5;
    int m0 = mq * 4;
    int h0 = p * SLICE;
    for (int idx = threadIdx.x; idx < 4 * SLICE; idx += Jd) {
        int r = idx / SLICE, h = idx - r * SLICE;
        xs[r][h] = X[(size_t)(m0 + r) * Hd + h0 + h];
    }
    __syncthreads();
    int j = threadIdx.x;
    float a0 = 0.f, a1 = 0.f, a2 = 0.f, a3 = 0.f;
    #pragma unroll 32
    for (int h = 0; h < SLICE; ++h) {
        float w = W[(size_t)(h0 + h) * Jd + j];
        a0 += xs[0][h] * w;
        a1 += xs[1][h] * w;
        a2 += xs[2][h] * w;
        a3 += xs[3][h] * w;
    }
    float* o = part + (size_t)p * (128 * Jd) + (size_t)m0 * Jd + j;
    o[0] = a0; o[Jd] = a1; o[2 * Jd] = a2; o[3 * Jd] = a3;
}

// ---------------------------------------------------------------------------
// K6: adjacency-apply + partial-sum + bias + relu:
//     O[b,i,j] = relu( sum_p sum_jj nadj[b,i,jj]*part[p][b*64+jj][j] + bias[j] )
//     Block per (b,i), blockDim = Jd/4.
// ---------------------------------------------------------------------------
template<int Jd, int KP>
__global__ void k_adjreluP(const float* __restrict__ nadj, const float* __restrict__ part,
                           const float* __restrict__ bias, float* __restrict__ O) {
    __shared__ float ar[KK];
    int blk = blockIdx.x;           // b*64 + i
    int b = blk >> 6;
    for (int idx = threadIdx.x; idx < KK; idx += blockDim.x)
        ar[idx] = nadj[(size_t)blk * KK + idx];
    __syncthreads();
    int t = threadIdx.x;            // [0, Jd/4)
    const float4* P4 = reinterpret_cast<const float4*>(part);
    float4 acc = reinterpret_cast<const float4*>(bias)[t];
    #pragma unroll
    for (int p = 0; p < KP; ++p) {
        #pragma unroll 8
        for (int jj = 0; jj < KK; ++jj) {
            float a = ar[jj];
            float4 x = P4[(size_t)(p * 128 + b * KK + jj) * (Jd / 4) + t];
            acc.x += a * x.x; acc.y += a * x.y; acc.z += a * x.z; acc.w += a * x.w;
        }
    }
    acc.x = fmaxf(acc.x, 0.f); acc.y = fmaxf(acc.y, 0.f);
    acc.z = fmaxf(acc.z, 0.f); acc.w = fmaxf(acc.w, 0.f);
    reinterpret_cast<float4*>(O + (size_t)blk * Jd)[t] = acc;
}

// ---------------------------------------------------------------------------
// K7: fused gemm3 + adjrelu3, all-LDS. Block per (b, col-half of 16).
//     xw3 = h2 @ w3 ;  h3 = relu(nadj @ xw3 + b3)
// ---------------------------------------------------------------------------
__global__ void __launch_bounds__(256) k_g3a3(const float* __restrict__ h2,
                                              const float* __restrict__ w3,
                                              const float* __restrict__ b3,
                                              const float* __restrict__ nadj,
                                              float* __restrict__ h3) {
    __shared__ float h2s[64][129];   // padded: conflict-free per-group rows
    __shared__ float w3s[128][16];
    __shared__ float xw3s[64][16];
    __shared__ float nadjs[64][65];  // padded
    __shared__ float b3s[16];
    int b = blockIdx.x >> 1, jh = blockIdx.x & 1;
    int j0 = jh * 16;
    int t = threadIdx.x;
    // stage h2[b] (64x128)
    for (int idx = t; idx < 2048; idx += 256) {
        int r = idx >> 5, c4 = (idx & 31) * 4;
        float4 v = *reinterpret_cast<const float4*>(h2 + ((size_t)b * KK + r) * H3 + c4);
        h2s[r][c4] = v.x; h2s[r][c4 + 1] = v.y; h2s[r][c4 + 2] = v.z; h2s[r][c4 + 3] = v.w;
    }
    // stage w3[:, j0:j0+16] (128x16)
    for (int idx = t; idx < 2048; idx += 256) {
        int kk = idx >> 4, jj = idx & 15;
        w3s[kk][jj] = w3[(size_t)kk * H4 + j0 + jj];
    }
    // stage nadj[b] (64x64)
    for (int idx = t; idx < 1024; idx += 256) {
        int r = idx >> 4, c4 = (idx & 15) * 4;
        float4 v = *reinterpret_cast<const float4*>(nadj + ((size_t)b * KK + r) * KK + c4);
        nadjs[r][c4] = v.x; nadjs[r][c4 + 1] = v.y; nadjs[r][c4 + 2] = v.z; nadjs[r][c4 + 3] = v.w;
    }
    if (t < 16) b3s[t] = b3[j0 + t];
    __syncthreads();
    int j = t & 15, r0 = t >> 4;     // r0 in [0,16): rows r0, r0+16, r0+32, r0+48
    {
        float a0 = 0.f, a1 = 0.f, a2 = 0.f, a3 = 0.f;
        #pragma unroll 8
        for (int kk = 0; kk < H3; ++kk) {
            float w = w3s[kk][j];
            a0 += h2s[r0][kk] * w;
            a1 += h2s[r0 + 16][kk] * w;
            a2 += h2s[r0 + 32][kk] * w;
            a3 += h2s[r0 + 48][kk] * w;
        }
        xw3s[r0][j] = a0; xw3s[r0 + 16][j] = a1;
        xw3s[r0 + 32][j] = a2; xw3s[r0 + 48][j] = a3;
    }
    __syncthreads();
    {
        float bv = b3s[j];
        float c0 = bv, c1 = bv, c2 = bv, c3 = bv;
        #pragma unroll 8
        for (int jj = 0; jj < KK; ++jj) {
            float x = xw3s[jj][j];
            c0 += nadjs[r0][jj] * x;
            c1 += nadjs[r0 + 16][jj] * x;
            c2 += nadjs[r0 + 32][jj] * x;
            c3 += nadjs[r0 + 48][jj] * x;
        }
        h3[((size_t)b * KK + r0) * H4 + j0 + j]      = fmaxf(c0, 0.f);
        h3[((size_t)b * KK + r0 + 16) * H4 + j0 + j] = fmaxf(c1, 0.f);
        h3[((size_t)b * KK + r0 + 32) * H4 + j0 + j] = fmaxf(c2, 0.f);
        h3[((size_t)b * KK + r0 + 48) * H4 + j0 + j] = fmaxf(c3, 0.f);
    }
}

// ---------------------------------------------------------------------------
// K8: fc1 split-K with fused residual head (out = h3@adj_w + adj_b + nf).
//     Block s owns flat rows [s*96,(s+1)*96) = one (krow, 96-col) slice.
//     512 blocks -> 2 blocks/CU, ~64KB in flight/CU -> HBM-saturated.
// ---------------------------------------------------------------------------
__global__ void __launch_bounds__(256) k_fc1(const float* __restrict__ h3,
                                             const float* __restrict__ adj_w,
                                             const float* __restrict__ adj_b,
                                             const float* __restrict__ nf,
                                             const float* __restrict__ W,
                                             float* __restrict__ part) {
    __shared__ __align__(16) float xs[2 * HBLK];
    __shared__ float h3s[2][H4];
    int s = blockIdx.x;
    int krow = s >> 3;              // 512/8 = 64 krows
    int c0 = (s & 7) * HBLK;        // column offset within the 768-wide row
    int t = threadIdx.x;
    if (t < 2 * H4) h3s[t >> 5][t & 31] = h3[(size_t)((t >> 5) * KK + krow) * H4 + (t & 31)];
    __syncthreads();
    if (t < 2 * HBLK) {
        int bb = t / HBLK, h = t - bb * HBLK;
        int hcol = c0 + h;
        float acc = adj_b[hcol] + nf[(size_t)(bb * KK + krow) * HH + hcol];
        #pragma unroll
        for (int kk = 0; kk < H4; ++kk) acc += h3s[bb][kk] * adj_w[(size_t)kk * HH + hcol];
        xs[t] = acc;
    }
    __syncthreads();
    if (t < 250) {
        float4 a0 = {0.f, 0.f, 0.f, 0.f}, a1 = {0.f, 0.f, 0.f, 0.f};
        const float4* W4 = reinterpret_cast<const float4*>(W) + t;
        int h0 = s * HBLK;
        #pragma unroll 8
        for (int hh = 0; hh < HBLK; ++hh) {
            float4 w = W4[(size_t)(h0 + hh) * 250];
            float x0 = xs[hh], x1 = xs[HBLK + hh];
            a0.x += x0 * w.x; a0.y += x0 * w.y; a0.z += x0 * w.z; a0.w += x0 * w.w;
            a1.x += x1 * w.x; a1.y += x1 * w.y; a1.z += x1 * w.z; a1.w += x1 * w.w;
        }
        float* p0 = part + (size_t)s * (2 * FC1N);
        reinterpret_cast<float4*>(p0)[t] = a0;
        reinterpret_cast<float4*>(p0 + FC1N)[t] = a1;
    }
}

// K9: reduce fc1 partials + bias + exact gelu -> y1[2,1000]
__global__ void k_fc1red(const float* __restrict__ part, const float* __restrict__ bias,
                         float* __restrict__ y1) {
    int g = blockIdx.x * 256 + threadIdx.x;
    if (g >= 2 * FC1N) return;
    int b = g / FC1N, j = g % FC1N;
    float acc = bias[j];
    #pragma unroll 16
    for (int s = 0; s < SPLIT; ++s) acc += part[(size_t)s * (2 * FC1N) + b * FC1N + j];
    y1[g] = gelu_exact(acc);
}

// K10: fused fc2(gelu)+fc3 -> d_out[2,7]. One 512-thread block.
__global__ void __launch_bounds__(512) k_fc23(const float* __restrict__ y1,
                                              const float* __restrict__ W2,
                                              const float* __restrict__ b2,
                                              const float* __restrict__ W3,
                                              const float* __restrict__ b3,
                                              float* __restrict__ out) {
    __shared__ float ys[2 * FC1N];
    __shared__ float psum[4][2][128];
    __shared__ float y2s[2][FC2N];
    int t = threadIdx.x;
    for (int idx = t; idx < 2 * FC1N; idx += 512) ys[idx] = y1[idx];
    __syncthreads();
    int j = t & 127, kp = t >> 7;
    float a0 = 0.f, a1 = 0.f;
    if (j < FC2N) {
        const float* ya = ys + kp * 250;
        const float* yb = ys + FC1N + kp * 250;
        const float* wp = W2 + (size_t)(kp * 250) * FC2N + j;
        #pragma unroll 4
        for (int h = 0; h < 250; ++h) {
            float w = wp[(size_t)h * FC2N];
            a0 += ya[h] * w;
            a1 += yb[h] * w;
        }
    }
    psum[kp][0][j] = a0;
    psum[kp][1][j] = a1;
    __syncthreads();
    if (t < 2 * FC2N) {
        int bb = t / FC2N, jj = t % FC2N;
        float acc = b2[jj] + psum[0][bb][jj] + psum[1][bb][jj]
                  + psum[2][bb][jj] + psum[3][bb][jj];
        y2s[bb][jj] = gelu_exact(acc);
    }
    __syncthreads();
    if (t < BB * NC) {
        int bb = t / NC, c = t % NC;
        float acc = b3[c];
        for (int h = 0; h < FC2N; ++h) acc += y2s[bb][h] * W3[h * NC + c];
        out[t] = acc;
    }
}

extern "C" void kernel_launch(void* const* d_in, const int* in_sizes, int n_in,
                              void* d_out, int out_size, void* d_ws, size_t ws_size,
                              hipStream_t stream) {
    const float* enc   = (const float*)d_in[0];
    const float* mask  = (const float*)d_in[1];
    const float* lm    = (const float*)d_in[2];
    const float* dptr  = (const float*)d_in[3];
    const float* aptr  = (const float*)d_in[4];
    const float* bptr  = (const float*)d_in[5];
    const float* w1    = (const float*)d_in[6];
    const float* b1    = (const float*)d_in[7];
    const float* w2    = (const float*)d_in[8];
    const float* b2    = (const float*)d_in[9];
    const float* w3    = (const float*)d_in[10];
    const float* b3    = (const float*)d_in[11];
    const float* adj_w = (const float*)d_in[12];
    const float* adj_b = (const float*)d_in[13];
    const float* fc1w  = (const float*)d_in[14];
    const float* fc1b  = (const float*)d_in[15];
    const float* fc2w  = (const float*)d_in[16];
    const float* fc2b  = (const float*)d_in[17];
    const float* fc3w  = (const float*)d_in[18];
    const float* fc3b  = (const float*)d_in[19];
    float* out = (float*)d_out;

    float* w = (float*)d_ws;
    float* pT    = w;                   // 16384
    float* G     = pT + 16384;          // 8192
    float* nadj  = G + 8192;            // 8192
    float* nf    = nadj + 8192;         // 98304
    float* part1 = nf + 98304;          // 4*128*256 = 131072
    float* h1    = part1 + 131072;      // 32768
    float* part2 = h1 + 32768;          // 4*128*128 = 65536
    float* h2    = part2 + 65536;       // 16384
    float* h3    = h2 + 16384;          // 4096
    float* partF = h3 + 4096;           // 512*2000 = 1024000
    float* y1    = partF + 1024000;     // 2000

    k_dist<<<BB * NN, 256, 0, stream>>>(enc, mask, lm, dptr, pT);
    k_graph<<<BB * KK * KK, 256, 0, stream>>>(pT, aptr, bptr, G);
    k_nodefeat<<<BB * KK, 256, 0, stream>>>(pT, enc, nf);
    k_nadj<<<BB, 64, 0, stream>>>(G, nadj);
    k_mmks<HH, H2, 4><<<128, H2, 0, stream>>>(nf, w1, part1);
    k_adjreluP<H2, 4><<<BB * KK, H2 / 4, 0, stream>>>(nadj, part1, b1, h1);
    k_mmks<H2, H3, 4><<<128, H3, 0, stream>>>(h1, w2, part2);
    k_adjreluP<H3, 4><<<BB * KK, H3 / 4, 0, stream>>>(nadj, part2, b2, h2);
    k_g3a3<<<4, 256, 0, stream>>>(h2, w3, b3, nadj, h3);
    k_fc1<<<SPLIT, 256, 0, stream>>>(h3, adj_w, adj_b, nf, fc1w, partF);
    k_fc1red<<<8, 256, 0, stream>>>(partF, fc1b, y1);
    k_fc23<<<1, 512, 0, stream>>>(y1, fc2w, fc2b, fc3w, fc3b, out);
}